// Round 1
// baseline (1165.035 us; speedup 1.0000x reference)
//
#include <hip/hip_runtime.h>
#include <hip/hip_bf16.h>
#include <stdint.h>

#define NTREES 16
#define TDEPTH 14
#define NPT    32767
#define HDIM   128

typedef __bf16 bf16x8 __attribute__((ext_vector_type(8)));
typedef float  f32x4  __attribute__((ext_vector_type(4)));

__device__ __forceinline__ float fsig(float x) {
    return __builtin_amdgcn_rcpf(1.0f + __expf(-x));
}
__device__ __forceinline__ float ftanh(float x) {
    // 1 - 2/(e^(2x)+1); saturates correctly for |x| large
    return 1.0f - 2.0f * __builtin_amdgcn_rcpf(__expf(2.0f * x) + 1.0f);
}

// ---------------- weight bf16 conversion + hg zero ----------------
__global__ __launch_bounds__(256) void prep_kernel(
    const float* __restrict__ W_iou, const float* __restrict__ U_iou,
    const float* __restrict__ U_f,
    __bf16* __restrict__ wiou_bf, __bf16* __restrict__ uiou_bf,
    __bf16* __restrict__ uf_bf, float* __restrict__ hg)
{
    int idx = blockIdx.x * 256 + threadIdx.x;
    if (idx < 49152)       wiou_bf[idx]          = (__bf16)W_iou[idx];
    else if (idx < 98304)  uiou_bf[idx - 49152]  = (__bf16)U_iou[idx - 49152];
    else if (idx < 114688) uf_bf[idx - 98304]    = (__bf16)U_f[idx - 98304];
    else if (idx < 116736) hg[idx - 114688]      = 0.0f;
}

// ---------------- leaf level: iou = x @ W_iou^T, apply node ----------------
// 128 leaf rows per block (contiguous node rows within one tree).
__global__ __launch_bounds__(256) void leaf_kernel(
    const float* __restrict__ feat, float* __restrict__ c,
    const __bf16* __restrict__ wiou_bf, const float* __restrict__ b_iou,
    __bf16* __restrict__ hbf)
{
    __shared__ __align__(16) __bf16 As[128 * 128];  // xor-swizzled 16B units
    const int t = threadIdx.x;
    const int blk = blockIdx.x;
    const int tree = blk >> 7, chunk = blk & 127;
    const int rowbase = tree * NPT + 16383 + chunk * 128;

    // stage A: fp32 feature rows -> bf16 LDS
    for (int idx = t; idx < 128 * 32; idx += 256) {
        int r = idx >> 5, c4 = idx & 31;
        const float4 v = *reinterpret_cast<const float4*>(
            feat + (size_t)(rowbase + r) * HDIM + c4 * 4);
        int u16 = (c4 >> 1) ^ (r & 7);
        __bf16* dst = As + r * 128 + u16 * 8 + (c4 & 1) * 4;
        dst[0] = (__bf16)v.x; dst[1] = (__bf16)v.y;
        dst[2] = (__bf16)v.z; dst[3] = (__bf16)v.w;
    }
    __syncthreads();

    const int wave = t >> 6, lane = t & 63;
    const int n15 = lane & 15, q = lane >> 4;
    int aoff[4];
    #pragma unroll
    for (int kk = 0; kk < 4; ++kk) aoff[kk] = ((kk * 4 + q) ^ (n15 & 7)) * 8;

    for (int jj = 0; jj < 2; ++jj) {
        const int jg = wave + jj * 4;            // j-group: cols jg*16..jg*16+15
        bf16x8 bfr[3][4];                        // i,o,u weight frags
        #pragma unroll
        for (int p = 0; p < 3; ++p) {
            const __bf16* bp = wiou_bf + (size_t)(p * 128 + jg * 16 + n15) * HDIM + q * 8;
            #pragma unroll
            for (int kk = 0; kk < 4; ++kk)
                bfr[p][kk] = *reinterpret_cast<const bf16x8*>(bp + kk * 32);
        }
        const int j = jg * 16 + n15;
        const float bi = b_iou[j], bo = b_iou[128 + j], bu = b_iou[256 + j];
        for (int mt = 0; mt < 8; ++mt) {
            bf16x8 afr[4];
            #pragma unroll
            for (int kk = 0; kk < 4; ++kk)
                afr[kk] = *reinterpret_cast<const bf16x8*>(As + (mt * 16 + n15) * 128 + aoff[kk]);
            f32x4 ai = {0,0,0,0}, ao = {0,0,0,0}, au = {0,0,0,0};
            #pragma unroll
            for (int kk = 0; kk < 4; ++kk) {
                ai = __builtin_amdgcn_mfma_f32_16x16x32_bf16(afr[kk], bfr[0][kk], ai, 0,0,0);
                ao = __builtin_amdgcn_mfma_f32_16x16x32_bf16(afr[kk], bfr[1][kk], ao, 0,0,0);
                au = __builtin_amdgcn_mfma_f32_16x16x32_bf16(afr[kk], bfr[2][kk], au, 0,0,0);
            }
            #pragma unroll
            for (int reg = 0; reg < 4; ++reg) {
                int r = mt * 16 + q * 4 + reg;
                size_t off = (size_t)(rowbase + r) * HDIM + j;
                float ci = c[off];
                float cn = fsig(ai[reg] + bi) * ftanh(au[reg] + bu) + ci;
                float hn = fsig(ao[reg] + bo) * ftanh(cn);
                c[off]   = cn;
                hbf[off] = (__bf16)hn;
            }
        }
    }
}

// ---------------- one internal level (32 nodes / block) ----------------
__global__ __launch_bounds__(256) void level_kernel(
    int l, int Mlev,
    float* __restrict__ c,
    const __bf16* __restrict__ uiou_bf, const __bf16* __restrict__ uf_bf,
    const float* __restrict__ b_iou, const float* __restrict__ ufb,
    __bf16* __restrict__ hbf)
{
    __shared__ __align__(16) __bf16 Hc[64 * 128];   // child h rows (swizzled)
    __shared__ __align__(16) __bf16 Ht[32 * 128];   // h_tild rows (swizzled)
    __shared__ float cagg[32 * 132];                // fp32, padded pitch
    const int t = threadIdx.x;
    const int blk32 = blockIdx.x * 32;
    const int nmask = (1 << l) - 1;

    // stage Hc: 64 contiguous-per-node child rows of bf16 h
    for (int idx = t; idx < 64 * 16; idx += 256) {
        int r = idx >> 4, s = idx & 15;
        int inode = blk32 + (r >> 1);
        uint4 v = {0, 0, 0, 0};
        if (inode < Mlev) {
            int tree = inode >> l, local = inode & nmask;
            int nloc = nmask + local;
            size_t crow = (size_t)tree * NPT + 2 * nloc + 1 + (r & 1);
            v = *reinterpret_cast<const uint4*>(hbf + crow * HDIM + s * 8);
        }
        *reinterpret_cast<uint4*>(Hc + r * 128 + ((s ^ (r & 7)) * 8)) = v;
    }
    __syncthreads();

    // Ht = Hc[2n] + Hc[2n+1]
    for (int idx = t; idx < 32 * 16; idx += 256) {
        int nno = idx >> 4, s = idx & 15;
        const __bf16* p0 = Hc + (2 * nno)     * 128 + ((s ^ ((2 * nno) & 7)) * 8);
        const __bf16* p1 = Hc + (2 * nno + 1) * 128 + ((s ^ ((2 * nno + 1) & 7)) * 8);
        __bf16* po = Ht + nno * 128 + ((s ^ (nno & 7)) * 8);
        #pragma unroll
        for (int e = 0; e < 8; ++e) po[e] = (__bf16)((float)p0[e] + (float)p1[e]);
    }
    __syncthreads();

    const int wave = t >> 6, lane = t & 63;
    const int n15 = lane & 15, q = lane >> 4;
    int aoff[4];
    #pragma unroll
    for (int kk = 0; kk < 4; ++kk) aoff[kk] = ((kk * 4 + q) ^ (n15 & 7)) * 8;

    // ---- F phase: F = sigmoid(Hc @ U_f^T + b); cagg into LDS ----
    {
        bf16x8 bfr[2][4];
        #pragma unroll
        for (int i = 0; i < 2; ++i) {
            int nt = wave + i * 4;
            const __bf16* bp = uf_bf + (size_t)(nt * 16 + n15) * HDIM + q * 8;
            #pragma unroll
            for (int kk = 0; kk < 4; ++kk)
                bfr[i][kk] = *reinterpret_cast<const bf16x8*>(bp + kk * 32);
        }
        for (int mt = 0; mt < 4; ++mt) {
            bf16x8 afr[4];
            #pragma unroll
            for (int kk = 0; kk < 4; ++kk)
                afr[kk] = *reinterpret_cast<const bf16x8*>(Hc + (mt * 16 + n15) * 128 + aoff[kk]);
            f32x4 acc0 = {0,0,0,0}, acc1 = {0,0,0,0};
            #pragma unroll
            for (int kk = 0; kk < 4; ++kk) {
                acc0 = __builtin_amdgcn_mfma_f32_16x16x32_bf16(afr[kk], bfr[0][kk], acc0, 0,0,0);
                acc1 = __builtin_amdgcn_mfma_f32_16x16x32_bf16(afr[kk], bfr[1][kk], acc1, 0,0,0);
            }
            #pragma unroll
            for (int i = 0; i < 2; ++i) {
                int nt = wave + i * 4;
                int j = nt * 16 + n15;
                float fb = ufb[j];
                f32x4 acc = i ? acc1 : acc0;
                #pragma unroll
                for (int p = 0; p < 2; ++p) {
                    int nl = mt * 8 + q * 2 + p;    // local node (rows 2nl,2nl+1)
                    int inode = blk32 + nl;
                    if (inode < Mlev) {
                        int tree = inode >> l, local = inode & nmask;
                        int nloc = nmask + local;
                        size_t crow = (size_t)tree * NPT + 2 * nloc + 1;
                        float c0 = c[crow * HDIM + j];
                        float c1 = c[(crow + 1) * HDIM + j];
                        float f0 = fsig(acc[2 * p] + fb);
                        float f1 = fsig(acc[2 * p + 1] + fb);
                        cagg[nl * 132 + j] = f0 * c0 + f1 * c1;
                    }
                }
            }
        }
    }
    __syncthreads();

    // ---- IOU phase: iou = Ht @ U_iou^T + b_iou; apply node ----
    for (int jj = 0; jj < 2; ++jj) {
        const int jg = wave + jj * 4;
        bf16x8 bfr[3][4];
        #pragma unroll
        for (int p = 0; p < 3; ++p) {
            const __bf16* bp = uiou_bf + (size_t)(p * 128 + jg * 16 + n15) * HDIM + q * 8;
            #pragma unroll
            for (int kk = 0; kk < 4; ++kk)
                bfr[p][kk] = *reinterpret_cast<const bf16x8*>(bp + kk * 32);
        }
        const int j = jg * 16 + n15;
        const float bi = b_iou[j], bo = b_iou[128 + j], bu = b_iou[256 + j];
        for (int mt = 0; mt < 2; ++mt) {
            bf16x8 afr[4];
            #pragma unroll
            for (int kk = 0; kk < 4; ++kk)
                afr[kk] = *reinterpret_cast<const bf16x8*>(Ht + (mt * 16 + n15) * 128 + aoff[kk]);
            f32x4 ai = {0,0,0,0}, ao = {0,0,0,0}, au = {0,0,0,0};
            #pragma unroll
            for (int kk = 0; kk < 4; ++kk) {
                ai = __builtin_amdgcn_mfma_f32_16x16x32_bf16(afr[kk], bfr[0][kk], ai, 0,0,0);
                ao = __builtin_amdgcn_mfma_f32_16x16x32_bf16(afr[kk], bfr[1][kk], ao, 0,0,0);
                au = __builtin_amdgcn_mfma_f32_16x16x32_bf16(afr[kk], bfr[2][kk], au, 0,0,0);
            }
            #pragma unroll
            for (int reg = 0; reg < 4; ++reg) {
                int nl = mt * 16 + q * 4 + reg;
                int inode = blk32 + nl;
                if (inode < Mlev) {
                    int tree = inode >> l, local = inode & nmask;
                    int nloc = nmask + local;
                    size_t nrow = (size_t)tree * NPT + nloc;
                    float cg = cagg[nl * 132 + j];
                    float cn = fsig(ai[reg] + bi) * ftanh(au[reg] + bu) + cg;
                    float hn = fsig(ao[reg] + bo) * ftanh(cn);
                    c[nrow * HDIM + j]   = cn;
                    hbf[nrow * HDIM + j] = (__bf16)hn;
                }
            }
        }
    }
}

// ---------------- avg-pool partial sums ----------------
__global__ __launch_bounds__(256) void pool_kernel(
    const __bf16* __restrict__ hbf, float* __restrict__ hg)
{
    const int t = threadIdx.x;
    const int tree = blockIdx.x >> 6, chunk = blockIdx.x & 63;
    const int col = t & 127, rg = t >> 7;
    const int r0 = chunk * 512;
    const int r1 = (r0 + 512 < NPT) ? (r0 + 512) : NPT;
    float s = 0.0f;
    for (int row = r0 + rg; row < r1; row += 2)
        s += (float)hbf[((size_t)tree * NPT + row) * HDIM + col];
    atomicAdd(&hg[tree * HDIM + col], s);
}

// ---------------- classifier + log_softmax ----------------
__global__ __launch_bounds__(256) void cls_kernel(
    const float* __restrict__ hg, const float* __restrict__ W_lin,
    const float* __restrict__ b_lin, float* __restrict__ out)
{
    __shared__ float lg[16 * 10];
    const int t = threadIdx.x;
    if (t < 160) {
        int b = t / 10, cc = t % 10;
        float s = b_lin[cc];
        const float inv = 1.0f / 32767.0f;
        for (int j = 0; j < HDIM; ++j)
            s += hg[b * HDIM + j] * inv * W_lin[cc * HDIM + j];
        lg[b * 10 + cc] = s;
    }
    __syncthreads();
    if (t < 16) {
        float m = lg[t * 10];
        for (int i = 1; i < 10; ++i) m = fmaxf(m, lg[t * 10 + i]);
        float sum = 0.0f;
        for (int i = 0; i < 10; ++i) sum += __expf(lg[t * 10 + i] - m);
        float lse = __logf(sum) + m;
        for (int i = 0; i < 10; ++i) out[t * 10 + i] = lg[t * 10 + i] - lse;
    }
}

extern "C" void kernel_launch(void* const* d_in, const int* in_sizes, int n_in,
                              void* d_out, int out_size, void* d_ws, size_t ws_size,
                              hipStream_t stream)
{
    const float* feat  = (const float*)d_in[0];
    char*        hbase = (char*)d_in[1];   // initial h is never read by the reference
    float*       c     = (float*)d_in[2];  // c updated in place (fp32)
    const float* W_iou = (const float*)d_in[3];
    const float* U_iou = (const float*)d_in[4];
    const float* b_iou = (const float*)d_in[5];
    const float* U_f_w = (const float*)d_in[6];
    const float* U_f_b = (const float*)d_in[7];
    const float* W_lin = (const float*)d_in[8];
    const float* b_lin = (const float*)d_in[9];

    __bf16* hbf = (__bf16*)hbase;          // 134,213,632 B working bf16 h
    const size_t WOFF = 134217728;         // 128 MiB; weight copies + hg live here
    __bf16* wiou_bf = (__bf16*)(hbase + WOFF);
    __bf16* uiou_bf = (__bf16*)(hbase + WOFF + 98304);
    __bf16* uf_bf   = (__bf16*)(hbase + WOFF + 196608);
    float*  hg      = (float*)(hbase + WOFF + 229376);

    prep_kernel<<<456, 256, 0, stream>>>(W_iou, U_iou, U_f_w, wiou_bf, uiou_bf, uf_bf, hg);
    leaf_kernel<<<2048, 256, 0, stream>>>(feat, c, wiou_bf, b_iou, hbf);
    for (int l = TDEPTH - 1; l >= 0; --l) {
        int Mlev = NTREES << l;
        int grid = (Mlev + 31) / 32;
        level_kernel<<<grid, 256, 0, stream>>>(l, Mlev, c, uiou_bf, uf_bf, b_iou, U_f_b, hbf);
    }
    pool_kernel<<<1024, 256, 0, stream>>>(hbf, hg);
    cls_kernel<<<1, 256, 0, stream>>>(hg, W_lin, b_lin, (float*)d_out);
}

// Round 2
// 938.778 us; speedup vs baseline: 1.2410x; 1.2410x over previous
//
#include <hip/hip_runtime.h>
#include <hip/hip_bf16.h>
#include <stdint.h>

#define NTREES 16
#define NPT    32767

typedef __bf16 bf16x8 __attribute__((ext_vector_type(8)));
typedef float  f32x4  __attribute__((ext_vector_type(4)));

__device__ __forceinline__ float fsig(float x) {
    return __builtin_amdgcn_rcpf(1.0f + __expf(-x));
}
__device__ __forceinline__ float ftanh(float x) {
    return 1.0f - 2.0f * __builtin_amdgcn_rcpf(__expf(2.0f * x) + 1.0f);
}
// swizzled bf16 LDS tile: element (row r, col j), row pitch 128
__device__ __forceinline__ int swz(int r, int j) {
    return r * 128 + (((j >> 3) ^ (r & 7)) << 3) + (j & 7);
}

// ---------------- weight bf16 conversion + hg zero ----------------
__global__ __launch_bounds__(256) void prep_kernel(
    const float* __restrict__ W_iou, const float* __restrict__ U_iou,
    const float* __restrict__ U_f,
    __bf16* __restrict__ wiou_bf, __bf16* __restrict__ uiou_bf,
    __bf16* __restrict__ uf_bf, float* __restrict__ hg)
{
    int idx = blockIdx.x * 256 + threadIdx.x;
    if (idx < 49152)       wiou_bf[idx]          = (__bf16)W_iou[idx];
    else if (idx < 98304)  uiou_bf[idx - 49152]  = (__bf16)U_iou[idx - 49152];
    else if (idx < 114688) uf_bf[idx - 98304]    = (__bf16)U_f[idx - 98304];
    else if (idx < 116736) hg[idx - 114688]      = 0.0f;
}

// ---------------- mega kernel: leaves + level13 + level12 ----------------
// block = 64-leaf subtree: 64 leaves -> 32 l13 nodes -> 16 l12 nodes.
// Only l12 h/c go to global; leaf/l13 h/c live in LDS. Pooling fused via atomics.
__global__ __launch_bounds__(256) void mega_kernel(
    const float* __restrict__ feat, const float* __restrict__ c0g,
    const __bf16* __restrict__ wiou, const __bf16* __restrict__ uiou,
    const __bf16* __restrict__ uf,
    const float* __restrict__ b_iou, const float* __restrict__ ufb,
    __bf16* __restrict__ hbf, __bf16* __restrict__ cbf, float* __restrict__ hg)
{
    __shared__ __align__(16) __bf16 HA[64 * 128];          // child h (swizzled)
    __shared__ __align__(16) __bf16 CA[64 * 136];          // child c (pitch 136)
    __shared__ __align__(16) unsigned char Sbuf[8192 + 32 * 132 * 4];
    __bf16* As   = (__bf16*)Sbuf;                          // phase A: feature tile
    __bf16* Ht   = (__bf16*)Sbuf;                          // phases B/C: h_tild
    float*  cagg = (float*)(Sbuf + 8192);

    const int t = threadIdx.x;
    const int tree = blockIdx.x >> 8, sub = blockIdx.x & 255;
    const size_t leafrow = (size_t)tree * NPT + 16383 + (size_t)sub * 64;

    // ---- stage feature tile (fp32 -> bf16, swizzled) ----
    for (int idx = t; idx < 64 * 32; idx += 256) {
        int r = idx >> 5, c4 = idx & 31;
        float4 v = *reinterpret_cast<const float4*>(feat + (leafrow + r) * 128 + c4 * 4);
        __bf16* dst = As + r * 128 + (((c4 >> 1) ^ (r & 7)) << 3) + ((c4 & 1) << 2);
        dst[0] = (__bf16)v.x; dst[1] = (__bf16)v.y; dst[2] = (__bf16)v.z; dst[3] = (__bf16)v.w;
    }
    __syncthreads();

    const int wave = t >> 6, lane = t & 63, n15 = lane & 15, q = lane >> 4;
    int aoff[4];
    #pragma unroll
    for (int kk = 0; kk < 4; ++kk) aoff[kk] = ((kk * 4 + q) ^ (n15 & 7)) << 3;
    float hsum0 = 0.f, hsum1 = 0.f;

    // U_f fragments + bias (used in phases B and C)
    bf16x8 ufr[2][4];
    float fb[2];
    #pragma unroll
    for (int i = 0; i < 2; ++i) {
        int nt = wave + i * 4;
        const __bf16* bp = uf + (size_t)(nt * 16 + n15) * 128 + q * 8;
        #pragma unroll
        for (int kk = 0; kk < 4; ++kk) ufr[i][kk] = *reinterpret_cast<const bf16x8*>(bp + kk * 32);
        fb[i] = ufb[nt * 16 + n15];
    }

    // ---- phase A: leaf GEMM + node apply -> HA/CA ----
    #pragma unroll
    for (int jj = 0; jj < 2; ++jj) {
        const int jg = wave + jj * 4;
        bf16x8 bfr[3][4];
        #pragma unroll
        for (int p = 0; p < 3; ++p) {
            const __bf16* bp = wiou + (size_t)(p * 128 + jg * 16 + n15) * 128 + q * 8;
            #pragma unroll
            for (int kk = 0; kk < 4; ++kk) bfr[p][kk] = *reinterpret_cast<const bf16x8*>(bp + kk * 32);
        }
        const int j = jg * 16 + n15;
        const float bi = b_iou[j], bo = b_iou[128 + j], bu = b_iou[256 + j];
        for (int mt = 0; mt < 4; ++mt) {
            bf16x8 afr[4];
            #pragma unroll
            for (int kk = 0; kk < 4; ++kk)
                afr[kk] = *reinterpret_cast<const bf16x8*>(As + (mt * 16 + n15) * 128 + aoff[kk]);
            f32x4 ai = {0,0,0,0}, ao = {0,0,0,0}, au = {0,0,0,0};
            #pragma unroll
            for (int kk = 0; kk < 4; ++kk) {
                ai = __builtin_amdgcn_mfma_f32_16x16x32_bf16(afr[kk], bfr[0][kk], ai, 0,0,0);
                ao = __builtin_amdgcn_mfma_f32_16x16x32_bf16(afr[kk], bfr[1][kk], ao, 0,0,0);
                au = __builtin_amdgcn_mfma_f32_16x16x32_bf16(afr[kk], bfr[2][kk], au, 0,0,0);
            }
            #pragma unroll
            for (int reg = 0; reg < 4; ++reg) {
                int r = mt * 16 + q * 4 + reg;
                float ci = c0g[(leafrow + r) * 128 + j];
                float cn = fsig(ai[reg] + bi) * ftanh(au[reg] + bu) + ci;
                float hn = fsig(ao[reg] + bo) * ftanh(cn);
                HA[swz(r, j)]    = (__bf16)hn;
                CA[r * 136 + j]  = (__bf16)cn;
                if (jj == 0) hsum0 += hn; else hsum1 += hn;
            }
        }
    }
    __syncthreads();   // As reads done; HA/CA complete

    // ---- phase B: level 13 (32 nodes, 64 child rows in LDS) ----
    for (int idx = t; idx < 32 * 16; idx += 256) {
        int nno = idx >> 4, s = idx & 15;
        const __bf16* p0 = HA + (2 * nno) * 128     + (((s ^ ((2 * nno) & 7))) << 3);
        const __bf16* p1 = HA + (2 * nno + 1) * 128 + (((s ^ ((2 * nno + 1) & 7))) << 3);
        __bf16* po = Ht + nno * 128 + (((s ^ (nno & 7))) << 3);
        #pragma unroll
        for (int e = 0; e < 8; ++e) po[e] = (__bf16)((float)p0[e] + (float)p1[e]);
    }
    for (int mt = 0; mt < 4; ++mt) {   // F phase
        bf16x8 afr[4];
        #pragma unroll
        for (int kk = 0; kk < 4; ++kk)
            afr[kk] = *reinterpret_cast<const bf16x8*>(HA + (mt * 16 + n15) * 128 + aoff[kk]);
        f32x4 a0 = {0,0,0,0}, a1 = {0,0,0,0};
        #pragma unroll
        for (int kk = 0; kk < 4; ++kk) {
            a0 = __builtin_amdgcn_mfma_f32_16x16x32_bf16(afr[kk], ufr[0][kk], a0, 0,0,0);
            a1 = __builtin_amdgcn_mfma_f32_16x16x32_bf16(afr[kk], ufr[1][kk], a1, 0,0,0);
        }
        #pragma unroll
        for (int i = 0; i < 2; ++i) {
            int j2 = (wave + i * 4) * 16 + n15;
            f32x4 acc = i ? a1 : a0;
            #pragma unroll
            for (int p = 0; p < 2; ++p) {
                int nl = mt * 8 + q * 2 + p;
                float cc0 = (float)CA[(2 * nl) * 136 + j2];
                float cc1 = (float)CA[(2 * nl + 1) * 136 + j2];
                cagg[nl * 132 + j2] = fsig(acc[2*p] + fb[i]) * cc0 + fsig(acc[2*p+1] + fb[i]) * cc1;
            }
        }
    }
    __syncthreads();   // Ht + cagg ready; HA/CA reads done
    #pragma unroll
    for (int jj = 0; jj < 2; ++jj) {   // IOU phase -> HB/CB into HA/CA rows 0..31
        const int jg = wave + jj * 4;
        bf16x8 bfr[3][4];
        #pragma unroll
        for (int p = 0; p < 3; ++p) {
            const __bf16* bp = uiou + (size_t)(p * 128 + jg * 16 + n15) * 128 + q * 8;
            #pragma unroll
            for (int kk = 0; kk < 4; ++kk) bfr[p][kk] = *reinterpret_cast<const bf16x8*>(bp + kk * 32);
        }
        const int j = jg * 16 + n15;
        const float bi = b_iou[j], bo = b_iou[128 + j], bu = b_iou[256 + j];
        for (int mt = 0; mt < 2; ++mt) {
            bf16x8 afr[4];
            #pragma unroll
            for (int kk = 0; kk < 4; ++kk)
                afr[kk] = *reinterpret_cast<const bf16x8*>(Ht + (mt * 16 + n15) * 128 + aoff[kk]);
            f32x4 ai = {0,0,0,0}, ao = {0,0,0,0}, au = {0,0,0,0};
            #pragma unroll
            for (int kk = 0; kk < 4; ++kk) {
                ai = __builtin_amdgcn_mfma_f32_16x16x32_bf16(afr[kk], bfr[0][kk], ai, 0,0,0);
                ao = __builtin_amdgcn_mfma_f32_16x16x32_bf16(afr[kk], bfr[1][kk], ao, 0,0,0);
                au = __builtin_amdgcn_mfma_f32_16x16x32_bf16(afr[kk], bfr[2][kk], au, 0,0,0);
            }
            #pragma unroll
            for (int reg = 0; reg < 4; ++reg) {
                int nl = mt * 16 + q * 4 + reg;
                float cg = cagg[nl * 132 + j];
                float cn = fsig(ai[reg] + bi) * ftanh(au[reg] + bu) + cg;
                float hn = fsig(ao[reg] + bo) * ftanh(cn);
                HA[swz(nl, j)]    = (__bf16)hn;
                CA[nl * 136 + j]  = (__bf16)cn;
                if (jj == 0) hsum0 += hn; else hsum1 += hn;
            }
        }
    }
    __syncthreads();

    // ---- phase C: level 12 (16 nodes, children = HA/CA rows 0..31) ----
    for (int idx = t; idx < 16 * 16; idx += 256) {
        int nno = idx >> 4, s = idx & 15;
        const __bf16* p0 = HA + (2 * nno) * 128     + (((s ^ ((2 * nno) & 7))) << 3);
        const __bf16* p1 = HA + (2 * nno + 1) * 128 + (((s ^ ((2 * nno + 1) & 7))) << 3);
        __bf16* po = Ht + nno * 128 + (((s ^ (nno & 7))) << 3);
        #pragma unroll
        for (int e = 0; e < 8; ++e) po[e] = (__bf16)((float)p0[e] + (float)p1[e]);
    }
    for (int mt = 0; mt < 2; ++mt) {   // F phase over 32 child rows
        bf16x8 afr[4];
        #pragma unroll
        for (int kk = 0; kk < 4; ++kk)
            afr[kk] = *reinterpret_cast<const bf16x8*>(HA + (mt * 16 + n15) * 128 + aoff[kk]);
        f32x4 a0 = {0,0,0,0}, a1 = {0,0,0,0};
        #pragma unroll
        for (int kk = 0; kk < 4; ++kk) {
            a0 = __builtin_amdgcn_mfma_f32_16x16x32_bf16(afr[kk], ufr[0][kk], a0, 0,0,0);
            a1 = __builtin_amdgcn_mfma_f32_16x16x32_bf16(afr[kk], ufr[1][kk], a1, 0,0,0);
        }
        #pragma unroll
        for (int i = 0; i < 2; ++i) {
            int j2 = (wave + i * 4) * 16 + n15;
            f32x4 acc = i ? a1 : a0;
            #pragma unroll
            for (int p = 0; p < 2; ++p) {
                int nl = mt * 8 + q * 2 + p;
                float cc0 = (float)CA[(2 * nl) * 136 + j2];
                float cc1 = (float)CA[(2 * nl + 1) * 136 + j2];
                cagg[nl * 132 + j2] = fsig(acc[2*p] + fb[i]) * cc0 + fsig(acc[2*p+1] + fb[i]) * cc1;
            }
        }
    }
    __syncthreads();
    const size_t p12row = (size_t)tree * NPT + 4095 + (size_t)sub * 16;
    #pragma unroll
    for (int jj = 0; jj < 2; ++jj) {   // IOU -> global
        const int jg = wave + jj * 4;
        bf16x8 bfr[3][4];
        #pragma unroll
        for (int p = 0; p < 3; ++p) {
            const __bf16* bp = uiou + (size_t)(p * 128 + jg * 16 + n15) * 128 + q * 8;
            #pragma unroll
            for (int kk = 0; kk < 4; ++kk) bfr[p][kk] = *reinterpret_cast<const bf16x8*>(bp + kk * 32);
        }
        const int j = jg * 16 + n15;
        const float bi = b_iou[j], bo = b_iou[128 + j], bu = b_iou[256 + j];
        bf16x8 afr[4];
        #pragma unroll
        for (int kk = 0; kk < 4; ++kk)
            afr[kk] = *reinterpret_cast<const bf16x8*>(Ht + n15 * 128 + aoff[kk]);
        f32x4 ai = {0,0,0,0}, ao = {0,0,0,0}, au = {0,0,0,0};
        #pragma unroll
        for (int kk = 0; kk < 4; ++kk) {
            ai = __builtin_amdgcn_mfma_f32_16x16x32_bf16(afr[kk], bfr[0][kk], ai, 0,0,0);
            ao = __builtin_amdgcn_mfma_f32_16x16x32_bf16(afr[kk], bfr[1][kk], ao, 0,0,0);
            au = __builtin_amdgcn_mfma_f32_16x16x32_bf16(afr[kk], bfr[2][kk], au, 0,0,0);
        }
        #pragma unroll
        for (int reg = 0; reg < 4; ++reg) {
            int nl = q * 4 + reg;
            float cg = cagg[nl * 132 + j];
            float cn = fsig(ai[reg] + bi) * ftanh(au[reg] + bu) + cg;
            float hn = fsig(ao[reg] + bo) * ftanh(cn);
            cbf[(p12row + nl) * 128 + j] = (__bf16)cn;
            hbf[(p12row + nl) * 128 + j] = (__bf16)hn;
            if (jj == 0) hsum0 += hn; else hsum1 += hn;
        }
    }

    // pooling partials: reduce over q, one atomic per col
    float v = hsum0;
    v += __shfl_xor(v, 16); v += __shfl_xor(v, 32);
    if (lane < 16) atomicAdd(&hg[tree * 128 + wave * 16 + lane], v);
    v = hsum1;
    v += __shfl_xor(v, 16); v += __shfl_xor(v, 32);
    if (lane < 16) atomicAdd(&hg[tree * 128 + (wave + 4) * 16 + lane], v);
}

// ---------------- one internal level (32 nodes / block), l in [5,11] ----------------
__global__ __launch_bounds__(256) void level_kernel(
    int l, const __bf16* __restrict__ uiou, const __bf16* __restrict__ uf,
    const float* __restrict__ b_iou, const float* __restrict__ ufb,
    __bf16* __restrict__ hbf, __bf16* __restrict__ cbf, float* __restrict__ hg)
{
    __shared__ __align__(16) __bf16 Hc[64 * 128];
    __shared__ __align__(16) __bf16 Ht[32 * 128];
    __shared__ float cagg[32 * 132];
    const int t = threadIdx.x;
    const int blk32 = blockIdx.x * 32;
    const int nmask = (1 << l) - 1;

    for (int idx = t; idx < 64 * 16; idx += 256) {
        int r = idx >> 4, s = idx & 15;
        int inode = blk32 + (r >> 1);
        int tree = inode >> l, local = inode & nmask;
        size_t crow = (size_t)tree * NPT + 2 * (nmask + local) + 1 + (r & 1);
        uint4 v = *reinterpret_cast<const uint4*>(hbf + crow * 128 + s * 8);
        *reinterpret_cast<uint4*>(Hc + r * 128 + ((s ^ (r & 7)) << 3)) = v;
    }
    __syncthreads();
    for (int idx = t; idx < 32 * 16; idx += 256) {
        int nno = idx >> 4, s = idx & 15;
        const __bf16* p0 = Hc + (2 * nno) * 128     + (((s ^ ((2 * nno) & 7))) << 3);
        const __bf16* p1 = Hc + (2 * nno + 1) * 128 + (((s ^ ((2 * nno + 1) & 7))) << 3);
        __bf16* po = Ht + nno * 128 + (((s ^ (nno & 7))) << 3);
        #pragma unroll
        for (int e = 0; e < 8; ++e) po[e] = (__bf16)((float)p0[e] + (float)p1[e]);
    }

    const int wave = t >> 6, lane = t & 63, n15 = lane & 15, q = lane >> 4;
    int aoff[4];
    #pragma unroll
    for (int kk = 0; kk < 4; ++kk) aoff[kk] = ((kk * 4 + q) ^ (n15 & 7)) << 3;
    float hsum0 = 0.f, hsum1 = 0.f;

    bf16x8 ufr[2][4];
    float fb[2];
    #pragma unroll
    for (int i = 0; i < 2; ++i) {
        int nt = wave + i * 4;
        const __bf16* bp = uf + (size_t)(nt * 16 + n15) * 128 + q * 8;
        #pragma unroll
        for (int kk = 0; kk < 4; ++kk) ufr[i][kk] = *reinterpret_cast<const bf16x8*>(bp + kk * 32);
        fb[i] = ufb[nt * 16 + n15];
    }
    for (int mt = 0; mt < 4; ++mt) {   // F phase
        bf16x8 afr[4];
        #pragma unroll
        for (int kk = 0; kk < 4; ++kk)
            afr[kk] = *reinterpret_cast<const bf16x8*>(Hc + (mt * 16 + n15) * 128 + aoff[kk]);
        f32x4 a0 = {0,0,0,0}, a1 = {0,0,0,0};
        #pragma unroll
        for (int kk = 0; kk < 4; ++kk) {
            a0 = __builtin_amdgcn_mfma_f32_16x16x32_bf16(afr[kk], ufr[0][kk], a0, 0,0,0);
            a1 = __builtin_amdgcn_mfma_f32_16x16x32_bf16(afr[kk], ufr[1][kk], a1, 0,0,0);
        }
        #pragma unroll
        for (int i = 0; i < 2; ++i) {
            int j2 = (wave + i * 4) * 16 + n15;
            f32x4 acc = i ? a1 : a0;
            #pragma unroll
            for (int p = 0; p < 2; ++p) {
                int nl = mt * 8 + q * 2 + p;
                int inode = blk32 + nl;
                int tree = inode >> l, local = inode & nmask;
                size_t crow = (size_t)tree * NPT + 2 * (nmask + local) + 1;
                float cc0 = (float)cbf[crow * 128 + j2];
                float cc1 = (float)cbf[(crow + 1) * 128 + j2];
                cagg[nl * 132 + j2] = fsig(acc[2*p] + fb[i]) * cc0 + fsig(acc[2*p+1] + fb[i]) * cc1;
            }
        }
    }
    __syncthreads();
    #pragma unroll
    for (int jj = 0; jj < 2; ++jj) {   // IOU phase
        const int jg = wave + jj * 4;
        bf16x8 bfr[3][4];
        #pragma unroll
        for (int p = 0; p < 3; ++p) {
            const __bf16* bp = uiou + (size_t)(p * 128 + jg * 16 + n15) * 128 + q * 8;
            #pragma unroll
            for (int kk = 0; kk < 4; ++kk) bfr[p][kk] = *reinterpret_cast<const bf16x8*>(bp + kk * 32);
        }
        const int j = jg * 16 + n15;
        const float bi = b_iou[j], bo = b_iou[128 + j], bu = b_iou[256 + j];
        for (int mt = 0; mt < 2; ++mt) {
            bf16x8 afr[4];
            #pragma unroll
            for (int kk = 0; kk < 4; ++kk)
                afr[kk] = *reinterpret_cast<const bf16x8*>(Ht + (mt * 16 + n15) * 128 + aoff[kk]);
            f32x4 ai = {0,0,0,0}, ao = {0,0,0,0}, au = {0,0,0,0};
            #pragma unroll
            for (int kk = 0; kk < 4; ++kk) {
                ai = __builtin_amdgcn_mfma_f32_16x16x32_bf16(afr[kk], bfr[0][kk], ai, 0,0,0);
                ao = __builtin_amdgcn_mfma_f32_16x16x32_bf16(afr[kk], bfr[1][kk], ao, 0,0,0);
                au = __builtin_amdgcn_mfma_f32_16x16x32_bf16(afr[kk], bfr[2][kk], au, 0,0,0);
            }
            #pragma unroll
            for (int reg = 0; reg < 4; ++reg) {
                int nl = mt * 16 + q * 4 + reg;
                int inode = blk32 + nl;
                int tree = inode >> l, local = inode & nmask;
                size_t nrow = (size_t)tree * NPT + nmask + local;
                float cg = cagg[nl * 132 + j];
                float cn = fsig(ai[reg] + bi) * ftanh(au[reg] + bu) + cg;
                float hn = fsig(ao[reg] + bo) * ftanh(cn);
                cbf[nrow * 128 + j] = (__bf16)cn;
                hbf[nrow * 128 + j] = (__bf16)hn;
                if (jj == 0) hsum0 += hn; else hsum1 += hn;
            }
        }
    }
    const int tree0 = blk32 >> l;   // l>=5: all 32 nodes in one tree
    float v = hsum0;
    v += __shfl_xor(v, 16); v += __shfl_xor(v, 32);
    if (lane < 16) atomicAdd(&hg[tree0 * 128 + wave * 16 + lane], v);
    v = hsum1;
    v += __shfl_xor(v, 16); v += __shfl_xor(v, 32);
    if (lane < 16) atomicAdd(&hg[tree0 * 128 + (wave + 4) * 16 + lane], v);
}

// ---------------- tail kernel: levels 4..0, one block per tree, all in LDS ----------------
__global__ __launch_bounds__(256) void tail_kernel(
    const __bf16* __restrict__ uiou, const __bf16* __restrict__ uf,
    const float* __restrict__ b_iou, const float* __restrict__ ufb,
    const __bf16* __restrict__ hbf, const __bf16* __restrict__ cbf,
    float* __restrict__ hg)
{
    __shared__ __align__(16) __bf16 Hp[2][32 * 128];
    __shared__ __align__(16) __bf16 Cp[2][32 * 136];
    __shared__ __align__(16) __bf16 HtT[16 * 128];
    __shared__ float caggT[16 * 132];
    const int t = threadIdx.x;
    const int tree = blockIdx.x;
    const size_t base5 = (size_t)tree * NPT + 31;   // level-5 rows

    for (int idx = t; idx < 32 * 16; idx += 256) {
        int r = idx >> 4, s = idx & 15;
        uint4 v = *reinterpret_cast<const uint4*>(hbf + (base5 + r) * 128 + s * 8);
        *reinterpret_cast<uint4*>(Hp[0] + r * 128 + ((s ^ (r & 7)) << 3)) = v;
        uint4 w = *reinterpret_cast<const uint4*>(cbf + (base5 + r) * 128 + s * 8);
        *reinterpret_cast<uint4*>(Cp[0] + r * 136 + s * 8) = w;
    }
    __syncthreads();

    const int wave = t >> 6, lane = t & 63, n15 = lane & 15, q = lane >> 4;
    int aoff[4];
    #pragma unroll
    for (int kk = 0; kk < 4; ++kk) aoff[kk] = ((kk * 4 + q) ^ (n15 & 7)) << 3;
    float hsum0 = 0.f, hsum1 = 0.f;

    bf16x8 ufr[2][4];
    float fb[2];
    #pragma unroll
    for (int i = 0; i < 2; ++i) {
        int nt = wave + i * 4;
        const __bf16* bp = uf + (size_t)(nt * 16 + n15) * 128 + q * 8;
        #pragma unroll
        for (int kk = 0; kk < 4; ++kk) ufr[i][kk] = *reinterpret_cast<const bf16x8*>(bp + kk * 32);
        fb[i] = ufb[nt * 16 + n15];
    }

    int cur = 0;
    for (int l = 4; l >= 0; --l) {
        const int M = 1 << l;
        __bf16* Hin  = Hp[cur];     __bf16* Cin  = Cp[cur];
        __bf16* Hout = Hp[cur ^ 1]; __bf16* Cout = Cp[cur ^ 1];
        for (int idx = t; idx < M * 16; idx += 256) {
            int nno = idx >> 4, s = idx & 15;
            const __bf16* p0 = Hin + (2 * nno) * 128     + (((s ^ ((2 * nno) & 7))) << 3);
            const __bf16* p1 = Hin + (2 * nno + 1) * 128 + (((s ^ ((2 * nno + 1) & 7))) << 3);
            __bf16* po = HtT + nno * 128 + (((s ^ (nno & 7))) << 3);
            #pragma unroll
            for (int e = 0; e < 8; ++e) po[e] = (__bf16)((float)p0[e] + (float)p1[e]);
        }
        const int mtF = (2 * M + 15) >> 4;
        for (int mt = 0; mt < mtF; ++mt) {   // F phase
            bf16x8 afr[4];
            #pragma unroll
            for (int kk = 0; kk < 4; ++kk)
                afr[kk] = *reinterpret_cast<const bf16x8*>(Hin + (mt * 16 + n15) * 128 + aoff[kk]);
            f32x4 a0 = {0,0,0,0}, a1 = {0,0,0,0};
            #pragma unroll
            for (int kk = 0; kk < 4; ++kk) {
                a0 = __builtin_amdgcn_mfma_f32_16x16x32_bf16(afr[kk], ufr[0][kk], a0, 0,0,0);
                a1 = __builtin_amdgcn_mfma_f32_16x16x32_bf16(afr[kk], ufr[1][kk], a1, 0,0,0);
            }
            #pragma unroll
            for (int i = 0; i < 2; ++i) {
                int j2 = (wave + i * 4) * 16 + n15;
                f32x4 acc = i ? a1 : a0;
                #pragma unroll
                for (int p = 0; p < 2; ++p) {
                    int nl = mt * 8 + q * 2 + p;
                    if (nl < M) {
                        float cc0 = (float)Cin[(2 * nl) * 136 + j2];
                        float cc1 = (float)Cin[(2 * nl + 1) * 136 + j2];
                        caggT[nl * 132 + j2] = fsig(acc[2*p] + fb[i]) * cc0
                                             + fsig(acc[2*p+1] + fb[i]) * cc1;
                    }
                }
            }
        }
        __syncthreads();
        #pragma unroll
        for (int jj = 0; jj < 2; ++jj) {   // IOU phase (single 16-row tile)
            const int jg = wave + jj * 4;
            bf16x8 bfr[3][4];
            #pragma unroll
            for (int p = 0; p < 3; ++p) {
                const __bf16* bp = uiou + (size_t)(p * 128 + jg * 16 + n15) * 128 + q * 8;
                #pragma unroll
                for (int kk = 0; kk < 4; ++kk) bfr[p][kk] = *reinterpret_cast<const bf16x8*>(bp + kk * 32);
            }
            const int j = jg * 16 + n15;
            const float bi = b_iou[j], bo = b_iou[128 + j], bu = b_iou[256 + j];
            bf16x8 afr[4];
            #pragma unroll
            for (int kk = 0; kk < 4; ++kk)
                afr[kk] = *reinterpret_cast<const bf16x8*>(HtT + n15 * 128 + aoff[kk]);
            f32x4 ai = {0,0,0,0}, ao = {0,0,0,0}, au = {0,0,0,0};
            #pragma unroll
            for (int kk = 0; kk < 4; ++kk) {
                ai = __builtin_amdgcn_mfma_f32_16x16x32_bf16(afr[kk], bfr[0][kk], ai, 0,0,0);
                ao = __builtin_amdgcn_mfma_f32_16x16x32_bf16(afr[kk], bfr[1][kk], ao, 0,0,0);
                au = __builtin_amdgcn_mfma_f32_16x16x32_bf16(afr[kk], bfr[2][kk], au, 0,0,0);
            }
            #pragma unroll
            for (int reg = 0; reg < 4; ++reg) {
                int nl = q * 4 + reg;
                if (nl < M) {
                    float cg = caggT[nl * 132 + j];
                    float cn = fsig(ai[reg] + bi) * ftanh(au[reg] + bu) + cg;
                    float hn = fsig(ao[reg] + bo) * ftanh(cn);
                    Hout[swz(nl, j)]   = (__bf16)hn;
                    Cout[nl * 136 + j] = (__bf16)cn;
                    if (jj == 0) hsum0 += hn; else hsum1 += hn;
                }
            }
        }
        __syncthreads();
        cur ^= 1;
    }
    float v = hsum0;
    v += __shfl_xor(v, 16); v += __shfl_xor(v, 32);
    if (lane < 16) atomicAdd(&hg[tree * 128 + wave * 16 + lane], v);
    v = hsum1;
    v += __shfl_xor(v, 16); v += __shfl_xor(v, 32);
    if (lane < 16) atomicAdd(&hg[tree * 128 + (wave + 4) * 16 + lane], v);
}

// ---------------- classifier + log_softmax ----------------
__global__ __launch_bounds__(256) void cls_kernel(
    const float* __restrict__ hg, const float* __restrict__ W_lin,
    const float* __restrict__ b_lin, float* __restrict__ out)
{
    __shared__ float lg[16 * 10];
    const int t = threadIdx.x;
    if (t < 160) {
        int b = t / 10, cc = t % 10;
        float s = b_lin[cc];
        const float inv = 1.0f / 32767.0f;
        for (int j = 0; j < 128; ++j)
            s += hg[b * 128 + j] * inv * W_lin[cc * 128 + j];
        lg[b * 10 + cc] = s;
    }
    __syncthreads();
    if (t < 16) {
        float m = lg[t * 10];
        for (int i = 1; i < 10; ++i) m = fmaxf(m, lg[t * 10 + i]);
        float sum = 0.0f;
        for (int i = 0; i < 10; ++i) sum += __expf(lg[t * 10 + i] - m);
        float lse = __logf(sum) + m;
        for (int i = 0; i < 10; ++i) out[t * 10 + i] = lg[t * 10 + i] - lse;
    }
}

extern "C" void kernel_launch(void* const* d_in, const int* in_sizes, int n_in,
                              void* d_out, int out_size, void* d_ws, size_t ws_size,
                              hipStream_t stream)
{
    const float* feat  = (const float*)d_in[0];
    const float* c0g   = (const float*)d_in[2];   // initial c, read-only (leaves)
    const float* W_iou = (const float*)d_in[3];
    const float* U_iou = (const float*)d_in[4];
    const float* b_iou = (const float*)d_in[5];
    const float* U_f_w = (const float*)d_in[6];
    const float* U_f_b = (const float*)d_in[7];
    const float* W_lin = (const float*)d_in[8];
    const float* b_lin = (const float*)d_in[9];

    char* ws = (char*)d_ws;                       // ws is ~1 GiB; we use ~269 MB
    __bf16* hbf     = (__bf16*)ws;                        // working h (bf16)
    __bf16* cbf     = (__bf16*)(ws + 134217728);          // working c (bf16)
    __bf16* wiou_bf = (__bf16*)(ws + 268435456);
    __bf16* uiou_bf = (__bf16*)(ws + 268435456 + 98304);
    __bf16* uf_bf   = (__bf16*)(ws + 268435456 + 196608);
    float*  hg      = (float*)(ws + 268435456 + 229376);

    prep_kernel<<<456, 256, 0, stream>>>(W_iou, U_iou, U_f_w, wiou_bf, uiou_bf, uf_bf, hg);
    mega_kernel<<<4096, 256, 0, stream>>>(feat, c0g, wiou_bf, uiou_bf, uf_bf,
                                          b_iou, U_f_b, hbf, cbf, hg);
    for (int l = 11; l >= 5; --l)
        level_kernel<<<(NTREES << l) / 32, 256, 0, stream>>>(l, uiou_bf, uf_bf,
                                                             b_iou, U_f_b, hbf, cbf, hg);
    tail_kernel<<<16, 256, 0, stream>>>(uiou_bf, uf_bf, b_iou, U_f_b, hbf, cbf, hg);
    cls_kernel<<<1, 256, 0, stream>>>(hg, W_lin, b_lin, (float*)d_out);
}